// Round 20
// baseline (187.265 us; speedup 1.0000x reference)
//
#include <hip/hip_runtime.h>
#include <hip/hip_bf16.h>

#define DEV static __device__ __forceinline__
#define AS1q __attribute__((address_space(1)))
#define AS3q __attribute__((address_space(3)))

typedef __attribute__((ext_vector_type(4))) float f32x4;
typedef __attribute__((ext_vector_type(16))) float f32x16;
typedef __attribute__((ext_vector_type(8))) short short8;
typedef __attribute__((ext_vector_type(4))) unsigned short u16x4;
typedef __attribute__((ext_vector_type(4))) unsigned int u32x4;

#define NB 4
#define NT 2048
#define NDM 1024
#define NH 16
#define NDH 64
#define NM (NB * NT)  // 8192 rows

DEV float bf2f(unsigned short u) {
  union { unsigned int i; float f; } x;
  x.i = ((unsigned int)u) << 16;
  return x.f;
}
DEV unsigned short f2bf(float f) {
  __hip_bfloat16 h = __float2bfloat16(f);
  return *reinterpret_cast<unsigned short*>(&h);
}
DEV unsigned int pack2bf(float lo, float hi) {
  return ((unsigned int)f2bf(hi) << 16) | (unsigned int)f2bf(lo);
}
DEV short8 mkfrag(unsigned int w0, unsigned int w1, unsigned int w2, unsigned int w3) {
  union { u32x4 u; short8 s; } x;
  x.u[0] = w0; x.u[1] = w1; x.u[2] = w2; x.u[3] = w3;
  return x.s;
}
// exchange lane i <-> lane i^32 (builtin returns BOTH results -> two distinct regs)
DEV void permswap(unsigned int& a, unsigned int& b) {
  auto r = __builtin_amdgcn_permlane32_swap(a, b, false, false);
  a = r[0]; b = r[1];
}
// lane^1 exchange via DPP quad_perm [1,0,3,2]
DEV float dpp_swap1(float v) {
  union { float f; int i; } x; x.f = v;
  int r = __builtin_amdgcn_update_dpp(0, x.i, 0xB1, 0xF, 0xF, true);
  union { int i; float f; } y; y.i = r;
  return y.f;
}

// ---------------- f32 -> bf16 convert ----------------
__global__ __launch_bounds__(256) void k_cvt_bf16(const float* __restrict__ in,
                                                  unsigned short* __restrict__ out,
                                                  int n8) {
  int i = blockIdx.x * 256 + threadIdx.x;
  if (i >= n8) return;
  const f32x4* p = (const f32x4*)(in + (size_t)i * 8);
  f32x4 a = p[0], b = p[1];
  short8 o;
  o[0] = (short)f2bf(a[0]); o[1] = (short)f2bf(a[1]);
  o[2] = (short)f2bf(a[2]); o[3] = (short)f2bf(a[3]);
  o[4] = (short)f2bf(b[0]); o[5] = (short)f2bf(b[1]);
  o[6] = (short)f2bf(b[2]); o[7] = (short)f2bf(b[3]);
  *(short8*)(out + (size_t)i * 8) = o;
}

// 4 weight matrices in one launch
__global__ __launch_bounds__(256) void k_cvt_w(const float* __restrict__ w0, const float* __restrict__ w1,
                                               const float* __restrict__ w2, const float* __restrict__ w3,
                                               unsigned short* __restrict__ o0, unsigned short* __restrict__ o1,
                                               unsigned short* __restrict__ o2, unsigned short* __restrict__ o3) {
  int i = blockIdx.x * 256 + threadIdx.x;
  int m = blockIdx.y;
  const float* in = (m == 0) ? w0 : (m == 1) ? w1 : (m == 2) ? w2 : w3;
  unsigned short* out = (m == 0) ? o0 : (m == 1) ? o1 : (m == 2) ? o2 : o3;
  const f32x4* p = (const f32x4*)(in + (size_t)i * 8);
  f32x4 a = p[0], b = p[1];
  short8 o;
  o[0] = (short)f2bf(a[0]); o[1] = (short)f2bf(a[1]);
  o[2] = (short)f2bf(a[2]); o[3] = (short)f2bf(a[3]);
  o[4] = (short)f2bf(b[0]); o[5] = (short)f2bf(b[1]);
  o[6] = (short)f2bf(b[2]); o[7] = (short)f2bf(b[3]);
  *(short8*)(out + (size_t)i * 8) = o;
}

// ---------------- RoPE table ----------------
__global__ __launch_bounds__(256) void k_rope_table(float2* __restrict__ tab) {
  int i = blockIdx.x * 256 + threadIdx.x;  // NT*32
  int t = i >> 5, f = i & 31;
  float inv = powf(10000.0f, -(float)f / 32.0f);
  float ang = (float)t * inv;
  tab[i] = make_float2(cosf(ang), sinf(ang));
}

// ---------------- GEMM core (best measured, R13): 128x128, BK=64, dbuf LDS 64KB ----
DEV void gemm_core(const unsigned short* __restrict__ Ab,
                   const unsigned short* __restrict__ Bb,
                   int Kdim, unsigned short* lds,
                   int tid, int wr, int wc, int lq, int gg,
                   f32x4 (&acc)[4][4]) {
  const int q0 = tid,       r0 = q0 >> 3; const int o0 = ((q0 & 7) ^ (r0 & 7)) * 8;
  const int q1 = tid + 256, r1 = q1 >> 3; const int o1 = ((q1 & 7) ^ (r1 & 7)) * 8;
  const int q2 = tid + 512, r2 = q2 >> 3; const int o2 = ((q2 & 7) ^ (r2 & 7)) * 8;
  const int q3 = tid + 768, r3 = q3 >> 3; const int o3 = ((q3 & 7) ^ (r3 & 7)) * 8;
  const unsigned short* pa0 = Ab + (size_t)r0 * Kdim + o0;
  const unsigned short* pa1 = Ab + (size_t)r1 * Kdim + o1;
  const unsigned short* pa2 = Ab + (size_t)r2 * Kdim + o2;
  const unsigned short* pa3 = Ab + (size_t)r3 * Kdim + o3;
  const unsigned short* pb0 = Bb + (size_t)r0 * Kdim + o0;
  const unsigned short* pb1 = Bb + (size_t)r1 * Kdim + o1;
  const unsigned short* pb2 = Bb + (size_t)r2 * Kdim + o2;
  const unsigned short* pb3 = Bb + (size_t)r3 * Kdim + o3;
  const int e0 = q0 * 8, e1 = q1 * 8, e2 = q2 * 8, e3 = q3 * 8;

  auto stage = [&](int buf, int ko) {
    unsigned short* LA = lds + buf * 8192;
    unsigned short* LB = lds + 16384 + buf * 8192;
    __builtin_amdgcn_global_load_lds((const AS1q void*)(pa0 + ko), (AS3q void*)(LA + e0), 16, 0, 0);
    __builtin_amdgcn_global_load_lds((const AS1q void*)(pa1 + ko), (AS3q void*)(LA + e1), 16, 0, 0);
    __builtin_amdgcn_global_load_lds((const AS1q void*)(pa2 + ko), (AS3q void*)(LA + e2), 16, 0, 0);
    __builtin_amdgcn_global_load_lds((const AS1q void*)(pa3 + ko), (AS3q void*)(LA + e3), 16, 0, 0);
    __builtin_amdgcn_global_load_lds((const AS1q void*)(pb0 + ko), (AS3q void*)(LB + e0), 16, 0, 0);
    __builtin_amdgcn_global_load_lds((const AS1q void*)(pb1 + ko), (AS3q void*)(LB + e1), 16, 0, 0);
    __builtin_amdgcn_global_load_lds((const AS1q void*)(pb2 + ko), (AS3q void*)(LB + e2), 16, 0, 0);
    __builtin_amdgcn_global_load_lds((const AS1q void*)(pb3 + ko), (AS3q void*)(LB + e3), 16, 0, 0);
  };

  const int xA = (wr + lq) & 7, xB = (wc + lq) & 7;
  const int rowA = (wr + lq) * 64, rowB = (wc + lq) * 64;
  const int cA0 = (gg ^ xA) * 8, cA1 = ((4 + gg) ^ xA) * 8;
  const int cB0 = (gg ^ xB) * 8, cB1 = ((4 + gg) ^ xB) * 8;

  const int NKT = Kdim >> 6;
  stage(0, 0);
  __syncthreads();
  int cur = 0;
  for (int t = 0; t < NKT; ++t) {
    if (t + 1 < NKT) stage(cur ^ 1, (t + 1) << 6);  // overlap with compute below
    const unsigned short* LA = lds + cur * 8192;
    const unsigned short* LB = lds + 16384 + cur * 8192;
    short8 af[4], bf[4];
#pragma unroll
    for (int i = 0; i < 4; ++i) af[i] = *(const short8*)&LA[rowA + i * 1024 + cA0];
#pragma unroll
    for (int j = 0; j < 4; ++j) bf[j] = *(const short8*)&LB[rowB + j * 1024 + cB0];
#pragma unroll
    for (int i = 0; i < 4; ++i)
#pragma unroll
      for (int j = 0; j < 4; ++j)
        acc[i][j] = __builtin_amdgcn_mfma_f32_16x16x32_bf16(af[i], bf[j], acc[i][j], 0, 0, 0);
#pragma unroll
    for (int i = 0; i < 4; ++i) af[i] = *(const short8*)&LA[rowA + i * 1024 + cA1];
#pragma unroll
    for (int j = 0; j < 4; ++j) bf[j] = *(const short8*)&LB[rowB + j * 1024 + cB1];
#pragma unroll
    for (int i = 0; i < 4; ++i)
#pragma unroll
      for (int j = 0; j < 4; ++j)
        acc[i][j] = __builtin_amdgcn_mfma_f32_16x16x32_bf16(af[i], bf[j], acc[i][j], 0, 0, 0);
    __syncthreads();  // drains stage loads + protects cur for next-iter overwrite
    cur ^= 1;
  }
}

// ---------------- fused QKV GEMM + RoPE + head/V transpose ----------------
__global__ __launch_bounds__(256) void k_gemm_qkv(const unsigned short* __restrict__ A,
                                                  const unsigned short* __restrict__ Bw,
                                                  const float* __restrict__ bq,
                                                  const float* __restrict__ bk,
                                                  const float* __restrict__ bv,
                                                  const float2* __restrict__ tab,
                                                  unsigned short* __restrict__ QH,
                                                  unsigned short* __restrict__ KH,
                                                  unsigned short* __restrict__ VT) {
  __shared__ unsigned short lds[4 * 8192];
  const int K = NDM;
  const int tid = threadIdx.x;
  const int lane = tid & 63;
  const int wave = tid >> 6;
  const int wr = (wave >> 1) * 64;
  const int wc = (wave & 1) * 64;
  const int lq = lane & 15;
  const int gg = lane >> 4;

  unsigned int nbx = gridDim.x;  // 24
  unsigned int bid = blockIdx.y * nbx + blockIdx.x;
  unsigned int cpx = (nbx * gridDim.y) >> 3;
  unsigned int swz = (bid & 7) * cpx + (bid >> 3);
  const int bn = swz % nbx, bm = swz / nbx;

  const unsigned short* Ab = A + (size_t)bm * 128 * K;
  const unsigned short* Bb = Bw + (size_t)bn * 128 * K;

  f32x4 acc[4][4] = {};
  gemm_core(Ab, Bb, K, lds, tid, wr, wc, lq, gg, acc);

  const int which = bn >> 3;            // 0:q 1:k 2:v (block-uniform)
  const int nloc = (bn & 7) * 128;
  const int rowb = bm * 128 + wr + (lane >> 4) * 4;
  const int colb = nloc + wc + lq;

  if (which == 2) {
#pragma unroll
    for (int i = 0; i < 4; ++i) {
#pragma unroll
      for (int j = 0; j < 4; ++j) {
        const int col = colb + j * 16;
        const float bs = bv[col];
        const int h = col >> 6, dh = col & 63;
        u16x4 w;
#pragma unroll
        for (int r = 0; r < 4; ++r) w[r] = f2bf(acc[i][j][r] + bs);
        const int row = rowb + i * 16;
        const int bb = row >> 11, t = row & (NT - 1);
        *(u16x4*)&VT[(((size_t)(bb * NH + h)) * NDH + dh) * NT + t] = w;
      }
    }
  } else {
    const float* bias = which ? bk : bq;
    unsigned short* Out = which ? KH : QH;
    const float sc = which ? 1.0f : 0.125f * 1.44269504088896f;  // Q: 1/sqrt(dh)*log2(e)
#pragma unroll
    for (int i = 0; i < 4; ++i) {
#pragma unroll
      for (int j = 0; j < 4; ++j) {
        const int col = colb + j * 16;
        const float bs = bias[col];
        const int h = col >> 6, dh = col & 63;
        const int pidx = dh >> 1;
        const bool odd = dh & 1;
#pragma unroll
        for (int r = 0; r < 4; ++r) {
          const int row = rowb + i * 16 + r;
          const int bb = row >> 11, t = row & (NT - 1);
          const float v = acc[i][j][r] + bs;
          const float pv = dpp_swap1(v);  // partner (even<->odd col) via DPP
          const float2 cs = tab[t * 32 + pidx];
          const float y = odd ? (pv * cs.y + v * cs.x) : (v * cs.x - pv * cs.y);
          Out[(((size_t)(bb * NH + h)) * NT + t) * NDH + dh] = f2bf(y * sc);
        }
      }
    }
  }
}

// ---------------- output GEMM (f32 out) ----------------
__global__ __launch_bounds__(256) void k_gemm_bt(const unsigned short* __restrict__ A,
                                                 const unsigned short* __restrict__ Bw,
                                                 const float* __restrict__ bias,
                                                 float* __restrict__ Cout,
                                                 int M, int N, int K) {
  __shared__ unsigned short lds[4 * 8192];
  const int tid = threadIdx.x;
  const int lane = tid & 63;
  const int wave = tid >> 6;
  const int wr = (wave >> 1) * 64;
  const int wc = (wave & 1) * 64;
  const int lq = lane & 15;
  const int gg = lane >> 4;

  unsigned int nbx = gridDim.x;
  unsigned int bid = blockIdx.y * nbx + blockIdx.x;
  unsigned int cpx = (nbx * gridDim.y) >> 3;
  unsigned int swz = (bid & 7) * cpx + (bid >> 3);
  const int bn = swz % nbx, bm = swz / nbx;

  const unsigned short* Ab = A + (size_t)bm * 128 * K;
  const unsigned short* Bb = Bw + (size_t)bn * 128 * K;

  f32x4 acc[4][4] = {};
  gemm_core(Ab, Bb, K, lds, tid, wr, wc, lq, gg, acc);

  const int rowb = bm * 128 + wr + (lane >> 4) * 4;
  const int colb = bn * 128 + wc + lq;
#pragma unroll
  for (int i = 0; i < 4; ++i) {
#pragma unroll
    for (int j = 0; j < 4; ++j) {
      const int col = colb + j * 16;
      const float bs = bias[col];
#pragma unroll
      for (int r = 0; r < 4; ++r) {
        const size_t idx = (size_t)(rowb + i * 16 + r) * N + col;
        Cout[idx] = acc[i][j][r] + bs;
      }
    }
  }
}

// ---------------- causal flash attention: KVBLK=128 staged tiles ----------------
// R20: stage a 128-kv tile per barrier (K [128][64], V [64][128]); compute two 64-wide
// sub-blocks per staged tile -> barrier+drain count HALVED (34 -> 17 on longest blocks).
// V tile rows now 256B (16 chunk-columns): 4-bit XOR -> 2-way conflicts (~free, m136);
// K stays 4-way (structural at 64-wide rows). LDS 64KB (2 blocks/CU, unchanged residency).
// 1024 blocks (64 bh x 16), 4 warps x 32 q-rows, longest-first; no-shift exp2 softmax;
// l via MFMA ones-trick; setprio around MFMA clusters.
__global__ __launch_bounds__(256, 2) void k_attn(const unsigned short* __restrict__ Qh,
                                                 const unsigned short* __restrict__ Kh,
                                                 const unsigned short* __restrict__ Vtp,
                                                 unsigned short* __restrict__ Ctx) {
  __shared__ unsigned short kl[2][128 * 64];  // 16KB each
  __shared__ unsigned short vl[2][64 * 128];  // 16KB each
  const int tid = threadIdx.x;
  const int wave = tid >> 6, lane = tid & 63;
  const int l31 = lane & 31, hi = lane >> 5;
  const int b0 = blockIdx.x;
  const int bh = (b0 & 7) * 8 + ((b0 >> 3) & 7);  // XCD-local bh grouping
  const int t = 15 - (b0 >> 6);                   // longest tiles dispatch first
  const int b = bh >> 4, h = bh & 15;

  const unsigned short* K = Kh + (size_t)bh * NT * NDH;
  const unsigned short* V = Vtp + (size_t)bh * NDH * NT;

  // staging (per 128-kv tile): K = 1024 chunks (8/row of 64 elems), V = 1024 chunks
  // (16/row of 128 elems); 256 threads x 4 chunks each per matrix.
  const unsigned short* pk[4];
  const unsigned short* pv[4];
  int ech[4];
#pragma unroll
  for (int s = 0; s < 4; ++s) {
    const int c = tid + 256 * s;
    const int krow = c >> 3, kcol = ((c & 7) ^ (krow & 7)) * 8;
    const int vrow = c >> 4, vcol = ((c & 15) ^ (vrow & 15)) * 8;
    pk[s] = K + (size_t)krow * NDH + kcol;   // + kv0*NDH at stage
    pv[s] = V + (size_t)vrow * NT + vcol;    // + kv0 at stage
    ech[s] = c * 8;
  }
  const int xe = (l31 & 7) << 3;   // K read swizzle (8 chunk cols)
  const int xv = l31 & 15;         // V read swizzle (16 chunk cols)

  auto stage = [&](int buf, int kv0) {
#pragma unroll
    for (int s = 0; s < 4; ++s)
      __builtin_amdgcn_global_load_lds((const AS1q void*)(pk[s] + (size_t)kv0 * NDH),
                                       (AS3q void*)(&kl[buf][ech[s]]), 16, 0, 0);
#pragma unroll
    for (int s = 0; s < 4; ++s)
      __builtin_amdgcn_global_load_lds((const AS1q void*)(pv[s] + kv0),
                                       (AS3q void*)(&vl[buf][ech[s]]), 16, 0, 0);
  };

  const int q0w = t * 128 + wave * 32;
  const int nkt = t + 1;  // 128-wide kv tiles

  const unsigned short* Qr = Qh + ((size_t)bh * NT + q0w + l31) * NDH + 8 * hi;
  short8 qf[4];
#pragma unroll
  for (int s = 0; s < 4; ++s) qf[s] = *(const short8*)&Qr[16 * s];

  short8 onesf;
#pragma unroll
  for (int s = 0; s < 8; ++s) onesf[s] = (short)0x3F80;  // bf16 1.0

  f32x16 ot0 = {}, ot1 = {}, lacc = {};

  stage(0, 0);
  __syncthreads();

  for (int kt = 0; kt < nkt; ++kt) {
    const int cur = kt & 1;
    const int kv0 = kt * 128;
    if (kt + 1 < nkt) stage(cur ^ 1, kv0 + 128);

    const unsigned short* kc = kl[cur];
    const unsigned short* vc = vl[cur];
#pragma unroll
    for (int sb = 0; sb < 2; ++sb) {
      const int kv0s = kv0 + sb * 64;
      if (kv0s <= q0w + 31) {  // warp-uniform causal skip
        const int rbase = (sb * 64 + l31) * 64;
        f32x16 st0 = {}, st1 = {};
        __builtin_amdgcn_s_setprio(1);
#pragma unroll
        for (int s = 0; s < 4; ++s) {
          const int co = (16 * s + 8 * hi) ^ xe;
          short8 k0 = *(const short8*)&kc[rbase + co];
          short8 k1 = *(const short8*)&kc[rbase + 32 * 64 + co];
          st0 = __builtin_amdgcn_mfma_f32_32x32x16_bf16(k0, qf[s], st0, 0, 0, 0);
          st1 = __builtin_amdgcn_mfma_f32_32x32x16_bf16(k1, qf[s], st1, 0, 0, 0);
        }
        __builtin_amdgcn_s_setprio(0);
        if (kv0s + 64 > q0w) {  // diagonal-straddling sub-blocks
          const int qg = q0w + l31;
#pragma unroll
          for (int r = 0; r < 16; ++r) {
            const int kr = kv0s + (r & 3) + 8 * (r >> 2) + 4 * hi;
            if (kr > qg) st0[r] = -1e30f;
            if (kr + 32 > qg) st1[r] = -1e30f;
          }
        }
        // no-shift softmax: p = exp2(s) directly (exp2(-1e30) -> 0)
#pragma unroll
        for (int r = 0; r < 16; ++r) st0[r] = exp2f(st0[r]);
#pragma unroll
        for (int r = 0; r < 16; ++r) st1[r] = exp2f(st1[r]);
        short8 pf[4];
#pragma unroll
        for (int ks = 0; ks < 4; ++ks) {
          const f32x16& sm = (ks & 2) ? st1 : st0;
          const int o = (ks & 1) * 8;
          unsigned int w0 = pack2bf(sm[o + 0], sm[o + 1]);
          unsigned int w2 = pack2bf(sm[o + 4], sm[o + 5]);
          permswap(w0, w2);
          unsigned int w1 = pack2bf(sm[o + 2], sm[o + 3]);
          unsigned int w3 = pack2bf(sm[o + 6], sm[o + 7]);
          permswap(w1, w3);
          pf[ks] = mkfrag(w0, w1, w2, w3);
        }
        __builtin_amdgcn_s_setprio(1);
#pragma unroll
        for (int ks = 0; ks < 4; ++ks) {
          const int cov = ((sb * 8 + 2 * ks + hi) ^ xv) * 8;
          short8 v0 = *(const short8*)&vc[l31 * 128 + cov];
          short8 v1 = *(const short8*)&vc[(32 + l31) * 128 + cov];
          ot0 = __builtin_amdgcn_mfma_f32_32x32x16_bf16(v0, pf[ks], ot0, 0, 0, 0);
          ot1 = __builtin_amdgcn_mfma_f32_32x32x16_bf16(v1, pf[ks], ot1, 0, 0, 0);
          lacc = __builtin_amdgcn_mfma_f32_32x32x16_bf16(onesf, pf[ks], lacc, 0, 0, 0);
        }
        __builtin_amdgcn_s_setprio(0);
      }
    }
    __syncthreads();
  }

  // epilogue: l[q] = lacc[0] (all rows identical; lane's col = its q)
  const float inv_l = 1.0f / lacc[0];
  unsigned short* dst = Ctx + ((size_t)(b * NT) + q0w + l31) * NDM + h * NDH;
#pragma unroll
  for (int dt = 0; dt < 2; ++dt) {
#pragma unroll
    for (int grp = 0; grp < 4; ++grp) {
      u16x4 w;
#pragma unroll
      for (int r = 0; r < 4; ++r) {
        const float v = (dt ? ot1[grp * 4 + r] : ot0[grp * 4 + r]) * inv_l;
        w[r] = f2bf(v);
      }
      *(u16x4*)&dst[dt * 32 + grp * 8 + 4 * hi] = w;
    }
  }
}

extern "C" void kernel_launch(void* const* d_in, const int* in_sizes, int n_in,
                              void* d_out, int out_size, void* d_ws, size_t ws_size,
                              hipStream_t stream) {
  const float* x  = (const float*)d_in[0];
  const float* Wq = (const float*)d_in[1];
  const float* bq = (const float*)d_in[2];
  const float* Wk = (const float*)d_in[3];
  const float* bk = (const float*)d_in[4];
  const float* Wv = (const float*)d_in[5];
  const float* bv = (const float*)d_in[6];
  const float* Wo = (const float*)d_in[7];
  const float* bo = (const float*)d_in[8];

  char* ws = (char*)d_ws;
  const size_t MB = 1024 * 1024;
  if (ws_size < 90 * MB) return;

  unsigned short* XB   = (unsigned short*)(ws + 0);        // 16MB
  unsigned short* WQB  = (unsigned short*)(ws + 16 * MB);  // WQB|WKB|WVB contiguous
  unsigned short* WKB  = (unsigned short*)(ws + 18 * MB);
  unsigned short* WVB  = (unsigned short*)(ws + 20 * MB);
  unsigned short* WOB  = (unsigned short*)(ws + 22 * MB);
  unsigned short* QH   = (unsigned short*)(ws + 24 * MB);
  unsigned short* KH   = (unsigned short*)(ws + 40 * MB);
  unsigned short* VT   = (unsigned short*)(ws + 56 * MB);
  unsigned short* CTX  = (unsigned short*)(ws + 72 * MB);
  float2* TAB          = (float2*)(ws + 88 * MB);          // 512KB

  // converts + tables
  k_cvt_bf16<<<(NM * NDM / 8) / 256, 256, 0, stream>>>(x, XB, NM * NDM / 8);
  dim3 gw((NDM * NDM / 8) / 256, 4);
  k_cvt_w<<<gw, 256, 0, stream>>>(Wq, Wk, Wv, Wo, WQB, WKB, WVB, WOB);
  k_rope_table<<<(NT * 32) / 256, 256, 0, stream>>>(TAB);

  // fused QKV projection + RoPE + transposes
  dim3 gq(3 * NDM / 128, NM / 128);
  k_gemm_qkv<<<gq, 256, 0, stream>>>(XB, WQB, bq, bk, bv, TAB, QH, KH, VT);

  // attention (1024 blocks: 64 bh x 16 tiles, longest-first, KVBLK=128)
  k_attn<<<NB * NH * 16, 256, 0, stream>>>(QH, KH, VT, CTX);

  // output projection (f32 out)
  dim3 go(NDM / 128, NM / 128);
  k_gemm_bt<<<go, 256, 0, stream>>>(CTX, WOB, bo, (float*)d_out, NM, NDM, NDM);
}

// Round 21
// 180.972 us; speedup vs baseline: 1.0348x; 1.0348x over previous
//
#include <hip/hip_runtime.h>
#include <hip/hip_bf16.h>

#define DEV static __device__ __forceinline__
#define AS1q __attribute__((address_space(1)))
#define AS3q __attribute__((address_space(3)))

typedef __attribute__((ext_vector_type(4))) float f32x4;
typedef __attribute__((ext_vector_type(16))) float f32x16;
typedef __attribute__((ext_vector_type(8))) short short8;
typedef __attribute__((ext_vector_type(4))) unsigned short u16x4;
typedef __attribute__((ext_vector_type(4))) unsigned int u32x4;

#define NB 4
#define NT 2048
#define NDM 1024
#define NH 16
#define NDH 64
#define NM (NB * NT)  // 8192 rows

DEV float bf2f(unsigned short u) {
  union { unsigned int i; float f; } x;
  x.i = ((unsigned int)u) << 16;
  return x.f;
}
DEV unsigned short f2bf(float f) {
  __hip_bfloat16 h = __float2bfloat16(f);
  return *reinterpret_cast<unsigned short*>(&h);
}
DEV unsigned int pack2bf(float lo, float hi) {
  return ((unsigned int)f2bf(hi) << 16) | (unsigned int)f2bf(lo);
}
DEV short8 mkfrag(unsigned int w0, unsigned int w1, unsigned int w2, unsigned int w3) {
  union { u32x4 u; short8 s; } x;
  x.u[0] = w0; x.u[1] = w1; x.u[2] = w2; x.u[3] = w3;
  return x.s;
}
// exchange lane i <-> lane i^32 (builtin returns BOTH results -> two distinct regs)
DEV void permswap(unsigned int& a, unsigned int& b) {
  auto r = __builtin_amdgcn_permlane32_swap(a, b, false, false);
  a = r[0]; b = r[1];
}
// lane^1 exchange via DPP quad_perm [1,0,3,2]
DEV float dpp_swap1(float v) {
  union { float f; int i; } x; x.f = v;
  int r = __builtin_amdgcn_update_dpp(0, x.i, 0xB1, 0xF, 0xF, true);
  union { int i; float f; } y; y.i = r;
  return y.f;
}

// ---------------- f32 -> bf16 convert ----------------
__global__ __launch_bounds__(256) void k_cvt_bf16(const float* __restrict__ in,
                                                  unsigned short* __restrict__ out,
                                                  int n8) {
  int i = blockIdx.x * 256 + threadIdx.x;
  if (i >= n8) return;
  const f32x4* p = (const f32x4*)(in + (size_t)i * 8);
  f32x4 a = p[0], b = p[1];
  short8 o;
  o[0] = (short)f2bf(a[0]); o[1] = (short)f2bf(a[1]);
  o[2] = (short)f2bf(a[2]); o[3] = (short)f2bf(a[3]);
  o[4] = (short)f2bf(b[0]); o[5] = (short)f2bf(b[1]);
  o[6] = (short)f2bf(b[2]); o[7] = (short)f2bf(b[3]);
  *(short8*)(out + (size_t)i * 8) = o;
}

// 4 weight matrices in one launch
__global__ __launch_bounds__(256) void k_cvt_w(const float* __restrict__ w0, const float* __restrict__ w1,
                                               const float* __restrict__ w2, const float* __restrict__ w3,
                                               unsigned short* __restrict__ o0, unsigned short* __restrict__ o1,
                                               unsigned short* __restrict__ o2, unsigned short* __restrict__ o3) {
  int i = blockIdx.x * 256 + threadIdx.x;
  int m = blockIdx.y;
  const float* in = (m == 0) ? w0 : (m == 1) ? w1 : (m == 2) ? w2 : w3;
  unsigned short* out = (m == 0) ? o0 : (m == 1) ? o1 : (m == 2) ? o2 : o3;
  const f32x4* p = (const f32x4*)(in + (size_t)i * 8);
  f32x4 a = p[0], b = p[1];
  short8 o;
  o[0] = (short)f2bf(a[0]); o[1] = (short)f2bf(a[1]);
  o[2] = (short)f2bf(a[2]); o[3] = (short)f2bf(a[3]);
  o[4] = (short)f2bf(b[0]); o[5] = (short)f2bf(b[1]);
  o[6] = (short)f2bf(b[2]); o[7] = (short)f2bf(b[3]);
  *(short8*)(out + (size_t)i * 8) = o;
}

// ---------------- RoPE table ----------------
__global__ __launch_bounds__(256) void k_rope_table(float2* __restrict__ tab) {
  int i = blockIdx.x * 256 + threadIdx.x;  // NT*32
  int t = i >> 5, f = i & 31;
  float inv = powf(10000.0f, -(float)f / 32.0f);
  float ang = (float)t * inv;
  tab[i] = make_float2(cosf(ang), sinf(ang));
}

// ---------------- GEMM core (best measured, R13): 128x128, BK=64, dbuf LDS 64KB ----
// T2 swizzle (128B rows span all 32 banks -> 0 conflicts); addressing hoisted;
// stage(t+1) before compute(t); one barrier per K-tile.
DEV void gemm_core(const unsigned short* __restrict__ Ab,
                   const unsigned short* __restrict__ Bb,
                   int Kdim, unsigned short* lds,
                   int tid, int wr, int wc, int lq, int gg,
                   f32x4 (&acc)[4][4]) {
  const int q0 = tid,       r0 = q0 >> 3; const int o0 = ((q0 & 7) ^ (r0 & 7)) * 8;
  const int q1 = tid + 256, r1 = q1 >> 3; const int o1 = ((q1 & 7) ^ (r1 & 7)) * 8;
  const int q2 = tid + 512, r2 = q2 >> 3; const int o2 = ((q2 & 7) ^ (r2 & 7)) * 8;
  const int q3 = tid + 768, r3 = q3 >> 3; const int o3 = ((q3 & 7) ^ (r3 & 7)) * 8;
  const unsigned short* pa0 = Ab + (size_t)r0 * Kdim + o0;
  const unsigned short* pa1 = Ab + (size_t)r1 * Kdim + o1;
  const unsigned short* pa2 = Ab + (size_t)r2 * Kdim + o2;
  const unsigned short* pa3 = Ab + (size_t)r3 * Kdim + o3;
  const unsigned short* pb0 = Bb + (size_t)r0 * Kdim + o0;
  const unsigned short* pb1 = Bb + (size_t)r1 * Kdim + o1;
  const unsigned short* pb2 = Bb + (size_t)r2 * Kdim + o2;
  const unsigned short* pb3 = Bb + (size_t)r3 * Kdim + o3;
  const int e0 = q0 * 8, e1 = q1 * 8, e2 = q2 * 8, e3 = q3 * 8;

  auto stage = [&](int buf, int ko) {
    unsigned short* LA = lds + buf * 8192;
    unsigned short* LB = lds + 16384 + buf * 8192;
    __builtin_amdgcn_global_load_lds((const AS1q void*)(pa0 + ko), (AS3q void*)(LA + e0), 16, 0, 0);
    __builtin_amdgcn_global_load_lds((const AS1q void*)(pa1 + ko), (AS3q void*)(LA + e1), 16, 0, 0);
    __builtin_amdgcn_global_load_lds((const AS1q void*)(pa2 + ko), (AS3q void*)(LA + e2), 16, 0, 0);
    __builtin_amdgcn_global_load_lds((const AS1q void*)(pa3 + ko), (AS3q void*)(LA + e3), 16, 0, 0);
    __builtin_amdgcn_global_load_lds((const AS1q void*)(pb0 + ko), (AS3q void*)(LB + e0), 16, 0, 0);
    __builtin_amdgcn_global_load_lds((const AS1q void*)(pb1 + ko), (AS3q void*)(LB + e1), 16, 0, 0);
    __builtin_amdgcn_global_load_lds((const AS1q void*)(pb2 + ko), (AS3q void*)(LB + e2), 16, 0, 0);
    __builtin_amdgcn_global_load_lds((const AS1q void*)(pb3 + ko), (AS3q void*)(LB + e3), 16, 0, 0);
  };

  const int xA = (wr + lq) & 7, xB = (wc + lq) & 7;
  const int rowA = (wr + lq) * 64, rowB = (wc + lq) * 64;
  const int cA0 = (gg ^ xA) * 8, cA1 = ((4 + gg) ^ xA) * 8;
  const int cB0 = (gg ^ xB) * 8, cB1 = ((4 + gg) ^ xB) * 8;

  const int NKT = Kdim >> 6;
  stage(0, 0);
  __syncthreads();
  int cur = 0;
  for (int t = 0; t < NKT; ++t) {
    if (t + 1 < NKT) stage(cur ^ 1, (t + 1) << 6);  // overlap with compute below
    const unsigned short* LA = lds + cur * 8192;
    const unsigned short* LB = lds + 16384 + cur * 8192;
    short8 af[4], bf[4];
#pragma unroll
    for (int i = 0; i < 4; ++i) af[i] = *(const short8*)&LA[rowA + i * 1024 + cA0];
#pragma unroll
    for (int j = 0; j < 4; ++j) bf[j] = *(const short8*)&LB[rowB + j * 1024 + cB0];
#pragma unroll
    for (int i = 0; i < 4; ++i)
#pragma unroll
      for (int j = 0; j < 4; ++j)
        acc[i][j] = __builtin_amdgcn_mfma_f32_16x16x32_bf16(af[i], bf[j], acc[i][j], 0, 0, 0);
#pragma unroll
    for (int i = 0; i < 4; ++i) af[i] = *(const short8*)&LA[rowA + i * 1024 + cA1];
#pragma unroll
    for (int j = 0; j < 4; ++j) bf[j] = *(const short8*)&LB[rowB + j * 1024 + cB1];
#pragma unroll
    for (int i = 0; i < 4; ++i)
#pragma unroll
      for (int j = 0; j < 4; ++j)
        acc[i][j] = __builtin_amdgcn_mfma_f32_16x16x32_bf16(af[i], bf[j], acc[i][j], 0, 0, 0);
    __syncthreads();  // drains stage loads + protects cur for next-iter overwrite
    cur ^= 1;
  }
}

// ---------------- fused QKV GEMM + RoPE + head/V transpose ----------------
__global__ __launch_bounds__(256) void k_gemm_qkv(const unsigned short* __restrict__ A,
                                                  const unsigned short* __restrict__ Bw,
                                                  const float* __restrict__ bq,
                                                  const float* __restrict__ bk,
                                                  const float* __restrict__ bv,
                                                  const float2* __restrict__ tab,
                                                  unsigned short* __restrict__ QH,
                                                  unsigned short* __restrict__ KH,
                                                  unsigned short* __restrict__ VT) {
  __shared__ unsigned short lds[4 * 8192];
  const int K = NDM;
  const int tid = threadIdx.x;
  const int lane = tid & 63;
  const int wave = tid >> 6;
  const int wr = (wave >> 1) * 64;
  const int wc = (wave & 1) * 64;
  const int lq = lane & 15;
  const int gg = lane >> 4;

  unsigned int nbx = gridDim.x;  // 24
  unsigned int bid = blockIdx.y * nbx + blockIdx.x;
  unsigned int cpx = (nbx * gridDim.y) >> 3;
  unsigned int swz = (bid & 7) * cpx + (bid >> 3);
  const int bn = swz % nbx, bm = swz / nbx;

  const unsigned short* Ab = A + (size_t)bm * 128 * K;
  const unsigned short* Bb = Bw + (size_t)bn * 128 * K;

  f32x4 acc[4][4] = {};
  gemm_core(Ab, Bb, K, lds, tid, wr, wc, lq, gg, acc);

  const int which = bn >> 3;            // 0:q 1:k 2:v (block-uniform)
  const int nloc = (bn & 7) * 128;
  const int rowb = bm * 128 + wr + (lane >> 4) * 4;
  const int colb = nloc + wc + lq;

  if (which == 2) {
#pragma unroll
    for (int i = 0; i < 4; ++i) {
#pragma unroll
      for (int j = 0; j < 4; ++j) {
        const int col = colb + j * 16;
        const float bs = bv[col];
        const int h = col >> 6, dh = col & 63;
        u16x4 w;
#pragma unroll
        for (int r = 0; r < 4; ++r) w[r] = f2bf(acc[i][j][r] + bs);
        const int row = rowb + i * 16;
        const int bb = row >> 11, t = row & (NT - 1);
        *(u16x4*)&VT[(((size_t)(bb * NH + h)) * NDH + dh) * NT + t] = w;
      }
    }
  } else {
    const float* bias = which ? bk : bq;
    unsigned short* Out = which ? KH : QH;
    const float sc = which ? 1.0f : 0.125f * 1.44269504088896f;  // Q: 1/sqrt(dh)*log2(e)
#pragma unroll
    for (int i = 0; i < 4; ++i) {
#pragma unroll
      for (int j = 0; j < 4; ++j) {
        const int col = colb + j * 16;
        const float bs = bias[col];
        const int h = col >> 6, dh = col & 63;
        const int pidx = dh >> 1;
        const bool odd = dh & 1;
#pragma unroll
        for (int r = 0; r < 4; ++r) {
          const int row = rowb + i * 16 + r;
          const int bb = row >> 11, t = row & (NT - 1);
          const float v = acc[i][j][r] + bs;
          const float pv = dpp_swap1(v);  // partner (even<->odd col) via DPP
          const float2 cs = tab[t * 32 + pidx];
          const float y = odd ? (pv * cs.y + v * cs.x) : (v * cs.x - pv * cs.y);
          Out[(((size_t)(bb * NH + h)) * NT + t) * NDH + dh] = f2bf(y * sc);
        }
      }
    }
  }
}

// ---------------- output GEMM (f32 out) ----------------
__global__ __launch_bounds__(256) void k_gemm_bt(const unsigned short* __restrict__ A,
                                                 const unsigned short* __restrict__ Bw,
                                                 const float* __restrict__ bias,
                                                 float* __restrict__ Cout,
                                                 int M, int N, int K) {
  __shared__ unsigned short lds[4 * 8192];
  const int tid = threadIdx.x;
  const int lane = tid & 63;
  const int wave = tid >> 6;
  const int wr = (wave >> 1) * 64;
  const int wc = (wave & 1) * 64;
  const int lq = lane & 15;
  const int gg = lane >> 4;

  unsigned int nbx = gridDim.x;
  unsigned int bid = blockIdx.y * nbx + blockIdx.x;
  unsigned int cpx = (nbx * gridDim.y) >> 3;
  unsigned int swz = (bid & 7) * cpx + (bid >> 3);
  const int bn = swz % nbx, bm = swz / nbx;

  const unsigned short* Ab = A + (size_t)bm * 128 * K;
  const unsigned short* Bb = Bw + (size_t)bn * 128 * K;

  f32x4 acc[4][4] = {};
  gemm_core(Ab, Bb, K, lds, tid, wr, wc, lq, gg, acc);

  const int rowb = bm * 128 + wr + (lane >> 4) * 4;
  const int colb = bn * 128 + wc + lq;
#pragma unroll
  for (int i = 0; i < 4; ++i) {
#pragma unroll
    for (int j = 0; j < 4; ++j) {
      const int col = colb + j * 16;
      const float bs = bias[col];
#pragma unroll
      for (int r = 0; r < 4; ++r) {
        const size_t idx = (size_t)(rowb + i * 16 + r) * N + col;
        Cout[idx] = acc[i][j][r] + bs;
      }
    }
  }
}

// ---------------- causal flash attention (R13 exact: best measured, no setprio) ----------
// 1024 blocks (64 bh x 16 tiles), 4 warps x 32 q-rows, longest-first; KVBLK=64
// double-buffered swizzled LDS; no-shift exp2 softmax; l via MFMA ones-trick.
// setprio removed: R14/R19/R20 all measured slower with it (barrier-locked blocks =
// m190's setprio-negative regime); R13 without it is the session minimum (181.55us).
__global__ __launch_bounds__(256, 2) void k_attn(const unsigned short* __restrict__ Qh,
                                                 const unsigned short* __restrict__ Kh,
                                                 const unsigned short* __restrict__ Vtp,
                                                 unsigned short* __restrict__ Ctx) {
  __shared__ unsigned short kl[2][64 * 64];
  __shared__ unsigned short vl[2][64 * 64];
  const int tid = threadIdx.x;
  const int wave = tid >> 6, lane = tid & 63;
  const int l31 = lane & 31, hi = lane >> 5;
  const int b0 = blockIdx.x;
  const int bh = (b0 & 7) * 8 + ((b0 >> 3) & 7);  // XCD-local bh grouping
  const int t = 15 - (b0 >> 6);                   // longest tiles dispatch first
  const int b = bh >> 4, h = bh & 15;

  const unsigned short* K = Kh + (size_t)bh * NT * NDH;
  const unsigned short* V = Vtp + (size_t)bh * NDH * NT;

  const int ch0 = tid, ch1 = tid + 256;
  const int sr0 = ch0 >> 3, sc0 = ((ch0 & 7) ^ (sr0 & 7)) * 8;
  const int sr1 = ch1 >> 3, sc1 = ((ch1 & 7) ^ (sr1 & 7)) * 8;
  const int xe = (l31 & 7) << 3;

  auto stage = [&](int buf, int kv0) {
    __builtin_amdgcn_global_load_lds(
        (const AS1q void*)(K + (size_t)(kv0 + sr0) * NDH + sc0),
        (AS3q void*)(&kl[buf][ch0 * 8]), 16, 0, 0);
    __builtin_amdgcn_global_load_lds(
        (const AS1q void*)(K + (size_t)(kv0 + sr1) * NDH + sc1),
        (AS3q void*)(&kl[buf][ch1 * 8]), 16, 0, 0);
    __builtin_amdgcn_global_load_lds(
        (const AS1q void*)(V + (size_t)sr0 * NT + kv0 + sc0),
        (AS3q void*)(&vl[buf][ch0 * 8]), 16, 0, 0);
    __builtin_amdgcn_global_load_lds(
        (const AS1q void*)(V + (size_t)sr1 * NT + kv0 + sc1),
        (AS3q void*)(&vl[buf][ch1 * 8]), 16, 0, 0);
  };

  const int q0w = t * 128 + wave * 32;
  const int nkv = 2 * t + 2;

  const unsigned short* Qr = Qh + ((size_t)bh * NT + q0w + l31) * NDH + 8 * hi;
  short8 qf[4];
#pragma unroll
  for (int s = 0; s < 4; ++s) qf[s] = *(const short8*)&Qr[16 * s];

  short8 onesf;
#pragma unroll
  for (int s = 0; s < 8; ++s) onesf[s] = (short)0x3F80;  // bf16 1.0

  f32x16 ot0 = {}, ot1 = {}, lacc = {};

  stage(0, 0);
  __syncthreads();

  for (int kb = 0; kb < nkv; ++kb) {
    const int cur = kb & 1;
    const int kv0 = kb * 64;
    if (kb + 1 < nkv) stage(cur ^ 1, kv0 + 64);

    if (kv0 <= q0w + 31) {  // warp-uniform causal skip (barrier still hit below)
      const unsigned short* kc = kl[cur];
      f32x16 st0 = {}, st1 = {};
#pragma unroll
      for (int s = 0; s < 4; ++s) {
        const int co = (16 * s + 8 * hi) ^ xe;
        short8 k0 = *(const short8*)&kc[l31 * 64 + co];
        short8 k1 = *(const short8*)&kc[(32 + l31) * 64 + co];
        st0 = __builtin_amdgcn_mfma_f32_32x32x16_bf16(k0, qf[s], st0, 0, 0, 0);
        st1 = __builtin_amdgcn_mfma_f32_32x32x16_bf16(k1, qf[s], st1, 0, 0, 0);
      }
      if (kv0 + 64 > q0w) {  // diagonal-straddling blocks
        const int qg = q0w + l31;
#pragma unroll
        for (int r = 0; r < 16; ++r) {
          const int kr = kv0 + (r & 3) + 8 * (r >> 2) + 4 * hi;
          if (kr > qg) st0[r] = -1e30f;
          if (kr + 32 > qg) st1[r] = -1e30f;
        }
      }
      // no-shift softmax: p = exp2(s) directly (exp2(-1e30) -> 0)
#pragma unroll
      for (int r = 0; r < 16; ++r) st0[r] = exp2f(st0[r]);
#pragma unroll
      for (int r = 0; r < 16; ++r) st1[r] = exp2f(st1[r]);
      short8 pf[4];
#pragma unroll
      for (int ks = 0; ks < 4; ++ks) {
        const f32x16& sm = (ks & 2) ? st1 : st0;
        const int o = (ks & 1) * 8;
        unsigned int w0 = pack2bf(sm[o + 0], sm[o + 1]);
        unsigned int w2 = pack2bf(sm[o + 4], sm[o + 5]);
        permswap(w0, w2);
        unsigned int w1 = pack2bf(sm[o + 2], sm[o + 3]);
        unsigned int w3 = pack2bf(sm[o + 6], sm[o + 7]);
        permswap(w1, w3);
        pf[ks] = mkfrag(w0, w1, w2, w3);
      }
      const unsigned short* vc = vl[cur];
#pragma unroll
      for (int ks = 0; ks < 4; ++ks) {
        const int co = (16 * ks + 8 * hi) ^ xe;
        short8 v0 = *(const short8*)&vc[l31 * 64 + co];
        short8 v1 = *(const short8*)&vc[(32 + l31) * 64 + co];
        ot0 = __builtin_amdgcn_mfma_f32_32x32x16_bf16(v0, pf[ks], ot0, 0, 0, 0);
        ot1 = __builtin_amdgcn_mfma_f32_32x32x16_bf16(v1, pf[ks], ot1, 0, 0, 0);
        lacc = __builtin_amdgcn_mfma_f32_32x32x16_bf16(onesf, pf[ks], lacc, 0, 0, 0);
      }
    }
    __syncthreads();
  }

  // epilogue: l[q] = lacc[0] (all rows identical; lane's col = its q)
  const float inv_l = 1.0f / lacc[0];
  unsigned short* dst = Ctx + ((size_t)(b * NT) + q0w + l31) * NDM + h * NDH;
#pragma unroll
  for (int dt = 0; dt < 2; ++dt) {
#pragma unroll
    for (int grp = 0; grp < 4; ++grp) {
      u16x4 w;
#pragma unroll
      for (int r = 0; r < 4; ++r) {
        const float v = (dt ? ot1[grp * 4 + r] : ot0[grp * 4 + r]) * inv_l;
        w[r] = f2bf(v);
      }
      *(u16x4*)&dst[dt * 32 + grp * 8 + 4 * hi] = w;
    }
  }
}

extern "C" void kernel_launch(void* const* d_in, const int* in_sizes, int n_in,
                              void* d_out, int out_size, void* d_ws, size_t ws_size,
                              hipStream_t stream) {
  const float* x  = (const float*)d_in[0];
  const float* Wq = (const float*)d_in[1];
  const float* bq = (const float*)d_in[2];
  const float* Wk = (const float*)d_in[3];
  const float* bk = (const float*)d_in[4];
  const float* Wv = (const float*)d_in[5];
  const float* bv = (const float*)d_in[6];
  const float* Wo = (const float*)d_in[7];
  const float* bo = (const float*)d_in[8];

  char* ws = (char*)d_ws;
  const size_t MB = 1024 * 1024;
  if (ws_size < 90 * MB) return;

  unsigned short* XB   = (unsigned short*)(ws + 0);        // 16MB
  unsigned short* WQB  = (unsigned short*)(ws + 16 * MB);  // WQB|WKB|WVB contiguous
  unsigned short* WKB  = (unsigned short*)(ws + 18 * MB);
  unsigned short* WVB  = (unsigned short*)(ws + 20 * MB);
  unsigned short* WOB  = (unsigned short*)(ws + 22 * MB);
  unsigned short* QH   = (unsigned short*)(ws + 24 * MB);
  unsigned short* KH   = (unsigned short*)(ws + 40 * MB);
  unsigned short* VT   = (unsigned short*)(ws + 56 * MB);
  unsigned short* CTX  = (unsigned short*)(ws + 72 * MB);
  float2* TAB          = (float2*)(ws + 88 * MB);          // 512KB

  // converts + tables
  k_cvt_bf16<<<(NM * NDM / 8) / 256, 256, 0, stream>>>(x, XB, NM * NDM / 8);
  dim3 gw((NDM * NDM / 8) / 256, 4);
  k_cvt_w<<<gw, 256, 0, stream>>>(Wq, Wk, Wv, Wo, WQB, WKB, WVB, WOB);
  k_rope_table<<<(NT * 32) / 256, 256, 0, stream>>>(TAB);

  // fused QKV projection + RoPE + transposes
  dim3 gq(3 * NDM / 128, NM / 128);
  k_gemm_qkv<<<gq, 256, 0, stream>>>(XB, WQB, bq, bk, bv, TAB, QH, KH, VT);

  // attention (1024 blocks: 64 bh x 16 tiles, longest-first)
  k_attn<<<NB * NH * 16, 256, 0, stream>>>(QH, KH, VT, CTX);

  // output projection (f32 out)
  dim3 go(NDM / 128, NM / 128);
  k_gemm_bt<<<go, 256, 0, stream>>>(CTX, WOB, bo, (float*)d_out, NM, NDM, NDM);
}